// Round 2
// baseline (808.835 us; speedup 1.0000x reference)
//
#include <hip/hip_runtime.h>

// GaussianKernel: out[B, HW, OUT] = exp(-(||x||^2 - 2 x.w + ||w||^2)) + b
// x: [B,H,W,C] fp32 (rows = 262144, C=32); w: [C,128]; b: [128]; out fp32.
//
// Round-1 post-mortem: allocator targeted 8 waves/EU (64 VGPR) and spilled the
// per-lane w arrays to scratch -> 1.9 GB of spill traffic (FETCH 1.65 GB).
// Fix: amdgpu_waves_per_eu(4,4) pins 4 waves/EU -> 128-VGPR budget; live set
// (w 64 + x 32 + misc) fits with no spill.

constexpr int C_DIM  = 32;
constexpr int OUT_DIM = 128;
constexpr int ROWS_PER_WAVE = 32;
constexpr int WAVES_PER_BLOCK = 4;
constexpr float LOG2E = 1.4426950408889634f;

__global__ __launch_bounds__(256)
__attribute__((amdgpu_waves_per_eu(4, 4)))
void gaussian_rbf_kernel(const float* __restrict__ x,
                         const float* __restrict__ w,
                         const float* __restrict__ bias,
                         float* __restrict__ out,
                         int total_rows)
{
    const int lane = threadIdx.x & 63;
    const int wid  = threadIdx.x >> 6;
    const long wave_global = (long)blockIdx.x * WAVES_PER_BLOCK + wid;
    const long row_base = wave_global * ROWS_PER_WAVE;
    if (row_base >= total_rows) return;

    // Lane owns output columns (2*lane, 2*lane+1): float2-coalesced w loads
    // and a single float2 store per row.
    const int o = 2 * lane;

    float w0[C_DIM], w1[C_DIM];
    float wsq0 = 0.f, wsq1 = 0.f;
#pragma unroll
    for (int c = 0; c < C_DIM; ++c) {
        const float2 wv = *reinterpret_cast<const float2*>(w + c * OUT_DIM + o);
        w0[c] = wv.x;
        w1[c] = wv.y;
        wsq0 = fmaf(wv.x, wv.x, wsq0);
        wsq1 = fmaf(wv.y, wv.y, wsq1);
    }
    const float2 bv = *reinterpret_cast<const float2*>(bias + o);
    // exp(-d) = 2^(-log2e*d); fold -log2e*||w||^2 into per-lane constants.
    const float base0 = -LOG2E * wsq0;
    const float base1 = -LOG2E * wsq1;

    const long row_end = (row_base + ROWS_PER_WAVE < (long)total_rows)
                           ? row_base + ROWS_PER_WAVE : (long)total_rows;

    for (long row = row_base; row < row_end; ++row) {
        // Broadcast-load the 32-float x row (all lanes same address; one L1
        // access per instruction, L2/HBM traffic stays at 32 MB total).
        const float4* xr = reinterpret_cast<const float4*>(x + row * C_DIM);
        float4 xv[8];
#pragma unroll
        for (int k = 0; k < 8; ++k) xv[k] = xr[k];

        float xsq = 0.f, d0 = 0.f, d1 = 0.f;
#pragma unroll
        for (int k = 0; k < 8; ++k) {
            xsq = fmaf(xv[k].x, xv[k].x, xsq);
            xsq = fmaf(xv[k].y, xv[k].y, xsq);
            xsq = fmaf(xv[k].z, xv[k].z, xsq);
            xsq = fmaf(xv[k].w, xv[k].w, xsq);
            d0  = fmaf(xv[k].x, w0[4*k+0], d0);
            d0  = fmaf(xv[k].y, w0[4*k+1], d0);
            d0  = fmaf(xv[k].z, w0[4*k+2], d0);
            d0  = fmaf(xv[k].w, w0[4*k+3], d0);
            d1  = fmaf(xv[k].x, w1[4*k+0], d1);
            d1  = fmaf(xv[k].y, w1[4*k+1], d1);
            d1  = fmaf(xv[k].z, w1[4*k+2], d1);
            d1  = fmaf(xv[k].w, w1[4*k+3], d1);
        }

        // arg = -log2e*xsq + 2*log2e*dot - log2e*wsq
        const float t0 = fmaf(xsq, -LOG2E, base0);
        const float t1 = fmaf(xsq, -LOG2E, base1);
        const float a0 = fmaf(d0, 2.f * LOG2E, t0);
        const float a1 = fmaf(d1, 2.f * LOG2E, t1);

        float2 res;
        res.x = exp2f(a0) + bv.x;   // v_exp_f32
        res.y = exp2f(a1) + bv.y;
        *reinterpret_cast<float2*>(out + row * OUT_DIM + o) = res;
    }
}

extern "C" void kernel_launch(void* const* d_in, const int* in_sizes, int n_in,
                              void* d_out, int out_size, void* d_ws, size_t ws_size,
                              hipStream_t stream) {
    const float* x = (const float*)d_in[0];
    const float* w = (const float*)d_in[1];
    const float* b = (const float*)d_in[2];
    float* out = (float*)d_out;

    const int total_rows = in_sizes[0] / C_DIM;  // 262144
    const int rows_per_block = ROWS_PER_WAVE * WAVES_PER_BLOCK;  // 128
    const int nblocks = (total_rows + rows_per_block - 1) / rows_per_block;  // 2048

    gaussian_rbf_kernel<<<nblocks, 256, 0, stream>>>(x, w, b, out, total_rows);
}

// Round 3
// 80.958 us; speedup vs baseline: 9.9907x; 9.9907x over previous
//
#include <hip/hip_runtime.h>

// GaussianKernel: out[row, o] = exp(-(||x_row||^2 - 2 x_row.w_o + ||w_o||^2)) + b[o]
// x: 262144 rows x 32; w: [32,128]; b: [128]; all fp32.
//
// Round-2 post-mortem: spills persisted at VGPR_Count=64 (FETCH 2.27 GB).
// Fix: one output column per lane (w footprint 32 floats, demand ~75 VGPR)
// + __launch_bounds__(256,2) (min 2 waves/EU -> 256-VGPR cap, room to not spill).

constexpr int C_DIM  = 32;
constexpr int OUT_DIM = 128;
constexpr int ROWS_PER_WAVE = 32;
constexpr float LOG2E = 1.4426950408889634f;

__global__ __launch_bounds__(256, 2)
void gaussian_rbf_kernel(const float* __restrict__ x,
                         const float* __restrict__ w,
                         const float* __restrict__ bias,
                         float* __restrict__ out,
                         int total_rows)
{
    const int lane = threadIdx.x & 63;
    const int wid  = threadIdx.x >> 6;
    const int colHalf = wid & 1;   // which 64-column half this wave owns
    const int rowGrp  = wid >> 1;  // which 32-row group this wave owns
    const int o = colHalf * 64 + lane;

    const int row_base = (blockIdx.x * 2 + rowGrp) * ROWS_PER_WAVE;
    if (row_base >= total_rows) return;

    // One w column per lane: 32 VGPRs. Coalesced dword loads (lane-consecutive o).
    float wc[C_DIM];
    float wsq = 0.f;
#pragma unroll
    for (int c = 0; c < C_DIM; ++c) {
        wc[c] = w[c * OUT_DIM + o];
        wsq = fmaf(wc[c], wc[c], wsq);
    }
    const float bo = bias[o];
    // exp(-d) = 2^(-log2e*d); fold -log2e*||w||^2 into a per-lane constant.
    const float base = -LOG2E * wsq;

    const int row_end = (row_base + ROWS_PER_WAVE < total_rows)
                          ? row_base + ROWS_PER_WAVE : total_rows;

    for (int row = row_base; row < row_end; ++row) {
        // Row index is wave-uniform; make it provable so the x-row broadcast
        // loads can become scalar loads (frees VGPRs, one fetch per row).
        const int urow = __builtin_amdgcn_readfirstlane(row);
        const float4* xr = reinterpret_cast<const float4*>(x + (long)urow * C_DIM);
        float4 xv[8];
#pragma unroll
        for (int k = 0; k < 8; ++k) xv[k] = xr[k];

        float xsq = 0.f, d = 0.f;
#pragma unroll
        for (int k = 0; k < 8; ++k) {
            xsq = fmaf(xv[k].x, xv[k].x, xsq);
            xsq = fmaf(xv[k].y, xv[k].y, xsq);
            xsq = fmaf(xv[k].z, xv[k].z, xsq);
            xsq = fmaf(xv[k].w, xv[k].w, xsq);
            d   = fmaf(xv[k].x, wc[4*k+0], d);
            d   = fmaf(xv[k].y, wc[4*k+1], d);
            d   = fmaf(xv[k].z, wc[4*k+2], d);
            d   = fmaf(xv[k].w, wc[4*k+3], d);
        }

        // arg = 2*log2e*dot - log2e*xsq - log2e*wsq
        const float a = fmaf(d, 2.f * LOG2E, fmaf(xsq, -LOG2E, base));
        // 64 lanes store 64 consecutive floats: 256 B coalesced.
        out[(long)row * OUT_DIM + o] = exp2f(a) + bo;
    }
}

extern "C" void kernel_launch(void* const* d_in, const int* in_sizes, int n_in,
                              void* d_out, int out_size, void* d_ws, size_t ws_size,
                              hipStream_t stream) {
    const float* x = (const float*)d_in[0];
    const float* w = (const float*)d_in[1];
    const float* b = (const float*)d_in[2];
    float* out = (float*)d_out;

    const int total_rows = in_sizes[0] / C_DIM;              // 262144
    const int rows_per_block = 2 * ROWS_PER_WAVE;            // 64
    const int nblocks = (total_rows + rows_per_block - 1) / rows_per_block;  // 4096

    gaussian_rbf_kernel<<<nblocks, 256, 0, stream>>>(x, w, b, out, total_rows);
}

// Round 5
// 60.055 us; speedup vs baseline: 13.4683x; 1.3481x over previous
//
#include <hip/hip_runtime.h>

// GaussianKernel: out[row, o] = exp(-(||x_row||^2 - 2 x_row.w_o + ||w_o||^2)) + b[o]
// x: 262144 rows x 32; w: [32,128]; b: [128]; all fp32.
//
// Round-3 post-mortem: traffic clean, but allocator sank wc[] loads into the
// row loop (VGPR_Count=24) -> 32 VMEM + addressing per row; plus per-row xsq
// (32 FMA) redundant across lanes. Fix: asm-pin wc[] in VGPRs; compute xsq
// cooperatively (2 lanes/row, shfl combine, LDS broadcast).
// (Round 4 was an infra failure — same kernel, re-benched.)

constexpr int C_DIM  = 32;
constexpr int OUT_DIM = 128;
constexpr int ROWS_PER_WAVE = 32;
constexpr float LOG2E = 1.4426950408889634f;

__global__ __launch_bounds__(256, 2)
void gaussian_rbf_kernel(const float* __restrict__ x,
                         const float* __restrict__ w,
                         const float* __restrict__ bias,
                         float* __restrict__ out,
                         int total_rows)
{
    // [rowGrp][r]: xsq of row (blockIdx*2+rowGrp)*32 + r. 256 B.
    __shared__ float lds_xsq[2][ROWS_PER_WAVE];

    const int lane = threadIdx.x & 63;
    const int wid  = threadIdx.x >> 6;
    const int colHalf = wid & 1;   // which 64-column half this wave owns
    const int rowGrp  = wid >> 1;  // which 32-row group this wave owns
    const int o = colHalf * 64 + lane;

    const int row_base = (blockIdx.x * 2 + rowGrp) * ROWS_PER_WAVE;
    if (row_base >= total_rows) return;

    // --- one w column per lane, pinned in VGPRs ---
    float wc[C_DIM];
    float wsq = 0.f;
#pragma unroll
    for (int c = 0; c < C_DIM; ++c) {
        wc[c] = w[c * OUT_DIM + o];
        wsq = fmaf(wc[c], wc[c], wsq);
    }
#pragma unroll
    for (int c = 0; c < C_DIM; ++c)
        asm volatile("" : "+v"(wc[c]));   // forbid rematerialization into the loop
    const float bo = bias[o];
    const float base = -LOG2E * wsq;      // fold -log2e*||w||^2

    // --- cooperative xsq: 2 lanes per row, 16 elems each, shfl_xor combine ---
    {
        const int r    = lane >> 1;
        const int half = lane & 1;
        const float4* xp = reinterpret_cast<const float4*>(
            x + (long)(row_base + r) * C_DIM + half * 16);
        float part = 0.f;
#pragma unroll
        for (int k = 0; k < 4; ++k) {
            const float4 v = xp[k];   // lane-consecutive 64B chunks: coalesced
            part = fmaf(v.x, v.x, part);
            part = fmaf(v.y, v.y, part);
            part = fmaf(v.z, v.z, part);
            part = fmaf(v.w, v.w, part);
        }
        const float full = part + __shfl_xor(part, 1);
        if (half == 0) lds_xsq[rowGrp][r] = full;
        // Wave-internal ds_write -> ds_read ordering is guaranteed (in-order LDS,
        // compiler lgkmcnt). The other colHalf wave writes identical values, so
        // no __syncthreads is needed.
    }

    const int row_end = (row_base + ROWS_PER_WAVE < total_rows)
                          ? row_base + ROWS_PER_WAVE : total_rows;

    for (int row = row_base; row < row_end; ++row) {
        // Row index is wave-uniform; readfirstlane makes it provable so the
        // x-row loads become s_load (scalar cache, frees VGPRs).
        const int urow = __builtin_amdgcn_readfirstlane(row);
        const float4* xr = reinterpret_cast<const float4*>(x + (long)urow * C_DIM);
        float4 xv[8];
#pragma unroll
        for (int k = 0; k < 8; ++k) xv[k] = xr[k];

        // 4 accumulators for dep-chain ILP
        float d0 = 0.f, d1 = 0.f, d2 = 0.f, d3 = 0.f;
#pragma unroll
        for (int k = 0; k < 8; k += 4) {
            d0 = fmaf(xv[k+0].x, wc[4*(k+0)+0], d0);
            d0 = fmaf(xv[k+0].y, wc[4*(k+0)+1], d0);
            d0 = fmaf(xv[k+0].z, wc[4*(k+0)+2], d0);
            d0 = fmaf(xv[k+0].w, wc[4*(k+0)+3], d0);
            d1 = fmaf(xv[k+1].x, wc[4*(k+1)+0], d1);
            d1 = fmaf(xv[k+1].y, wc[4*(k+1)+1], d1);
            d1 = fmaf(xv[k+1].z, wc[4*(k+1)+2], d1);
            d1 = fmaf(xv[k+1].w, wc[4*(k+1)+3], d1);
            d2 = fmaf(xv[k+2].x, wc[4*(k+2)+0], d2);
            d2 = fmaf(xv[k+2].y, wc[4*(k+2)+1], d2);
            d2 = fmaf(xv[k+2].z, wc[4*(k+2)+2], d2);
            d2 = fmaf(xv[k+2].w, wc[4*(k+2)+3], d2);
            d3 = fmaf(xv[k+3].x, wc[4*(k+3)+0], d3);
            d3 = fmaf(xv[k+3].y, wc[4*(k+3)+1], d3);
            d3 = fmaf(xv[k+3].z, wc[4*(k+3)+2], d3);
            d3 = fmaf(xv[k+3].w, wc[4*(k+3)+3], d3);
        }
        const float d = (d0 + d1) + (d2 + d3);

        const float xsq = lds_xsq[rowGrp][row - row_base];  // uniform-addr broadcast
        const float t = fmaf(xsq, -LOG2E, base);
        const float a = fmaf(d, 2.f * LOG2E, t);
        // 64 lanes store 64 consecutive floats: 256 B coalesced.
        out[(long)row * OUT_DIM + o] = exp2f(a) + bo;
    }
}

extern "C" void kernel_launch(void* const* d_in, const int* in_sizes, int n_in,
                              void* d_out, int out_size, void* d_ws, size_t ws_size,
                              hipStream_t stream) {
    const float* x = (const float*)d_in[0];
    const float* w = (const float*)d_in[1];
    const float* b = (const float*)d_in[2];
    float* out = (float*)d_out;

    const int total_rows = in_sizes[0] / C_DIM;              // 262144
    const int rows_per_block = 2 * ROWS_PER_WAVE;            // 64
    const int nblocks = (total_rows + rows_per_block - 1) / rows_per_block;  // 4096

    gaussian_rbf_kernel<<<nblocks, 256, 0, stream>>>(x, w, b, out, total_rows);
}